// Round 3
// baseline (631.760 us; speedup 1.0000x reference)
//
#include <hip/hip_runtime.h>
#include <stdint.h>
#include <stddef.h>

// Problem constants (DINOv2 self-attention)
#define SQ     1370              // sequence length
#define SP     1376              // padded seq for V^T rows (16B-aligned stride)
#define NBATCH 8
#define NHEADS 16
#define DH     64                // head dim
#define DM     1024              // model dim
#define MROWS  (NBATCH * SQ)     // 10960 flattened rows

typedef _Float16 f16;
typedef __attribute__((ext_vector_type(8))) _Float16 f16x8;
typedef __attribute__((ext_vector_type(4))) _Float16 f16x4;
typedef __attribute__((ext_vector_type(4))) float    f32x4;

#define MFMA_16x16x32_F16(a, b, c) __builtin_amdgcn_mfma_f32_16x16x32_f16((a), (b), (c), 0, 0, 0)

// ---------------------------------------------------------------------------
// Kernel 1: fused QKV projection GEMM (x @ W^T + b), fp32 in, f16 out.
// Q,K written [B*H, S, DH]; V written TRANSPOSED [B*H, DH, SP] so the
// attention PV B-fragment is a contiguous 16B global load (no LDS transpose).
// Tile: 128x128, BK=32, 256 threads = 4 waves (2x2 of 64x64 per-wave tiles).
// ---------------------------------------------------------------------------
__global__ __launch_bounds__(256) void qkv_gemm_kernel(
    const float* __restrict__ hs,
    const float* __restrict__ Wq, const float* __restrict__ bq,
    const float* __restrict__ Wk, const float* __restrict__ bk,
    const float* __restrict__ Wv, const float* __restrict__ bv,
    f16* __restrict__ Qo, f16* __restrict__ Ko, f16* __restrict__ Vto)
{
    __shared__ f16 As[128][40];   // +8 pad: 16B-aligned rows, 2-way banks (free)
    __shared__ f16 Bs[128][40];

    const float* W; const float* bias;
    if (blockIdx.z == 0)      { W = Wq; bias = bq; }
    else if (blockIdx.z == 1) { W = Wk; bias = bk; }
    else                      { W = Wv; bias = bv; }

    const int m0   = blockIdx.x * 128;
    const int n0   = blockIdx.y * 128;
    const int t    = threadIdx.x;
    const int lane = t & 63;
    const int wid  = t >> 6;
    const int wm   = (wid >> 1) * 64;
    const int wn   = (wid & 1) * 64;
    const int lr   = lane & 15;
    const int quad = lane >> 4;

    f32x4 acc[4][4];
#pragma unroll
    for (int i = 0; i < 4; i++)
#pragma unroll
        for (int j = 0; j < 4; j++) acc[i][j] = (f32x4){0.f, 0.f, 0.f, 0.f};

    const int srow = t >> 3;        // 0..31
    const int scol = (t & 7) * 4;   // 0..28

    for (int k0 = 0; k0 < DM; k0 += 32) {
        __syncthreads();
#pragma unroll
        for (int rr = 0; rr < 4; rr++) {
            const int row = rr * 32 + srow;
            int gm = m0 + row; if (gm >= MROWS) gm = MROWS - 1;
            const float4 va = *(const float4*)(hs + (size_t)gm * DM + k0 + scol);
            *(f16x4*)&As[row][scol] =
                (f16x4){(f16)va.x, (f16)va.y, (f16)va.z, (f16)va.w};
            const float4 vb = *(const float4*)(W + (size_t)(n0 + row) * DM + k0 + scol);
            *(f16x4*)&Bs[row][scol] =
                (f16x4){(f16)vb.x, (f16)vb.y, (f16)vb.z, (f16)vb.w};
        }
        __syncthreads();

        f16x8 af[4], bf[4];
#pragma unroll
        for (int i = 0; i < 4; i++) {
            af[i] = *(const f16x8*)&As[wm + i * 16 + lr][quad * 8];
            bf[i] = *(const f16x8*)&Bs[wn + i * 16 + lr][quad * 8];
        }
#pragma unroll
        for (int i = 0; i < 4; i++)
#pragma unroll
            for (int j = 0; j < 4; j++)
                acc[i][j] = MFMA_16x16x32_F16(af[i], bf[j], acc[i][j]);
    }

    // Epilogue. C/D layout: row = quad*4+reg, col = lane&15 (m89-verified).
#pragma unroll
    for (int j = 0; j < 4; j++) {
        const int n  = n0 + wn + j * 16 + lr;
        const float bv_ = bias[n];
        const int h = n >> 6, d = n & 63;
#pragma unroll
        for (int i = 0; i < 4; i++) {
#pragma unroll
            for (int r = 0; r < 4; r++) {
                const int m = m0 + wm + i * 16 + quad * 4 + r;
                if (m < MROWS) {
                    const int b = m / SQ, s = m % SQ;
                    const f16 val = (f16)(acc[i][j][r] + bv_);
                    if (blockIdx.z == 2) {
                        // V^T: [bh, d, s] stride SP
                        Vto[((size_t)((b * NHEADS + h) * DH + d)) * SP + s] = val;
                    } else {
                        f16* outp = (blockIdx.z == 0) ? Qo : Ko;
                        outp[(((size_t)(b * NHEADS + h)) * SQ + s) * DH + d] = val;
                    }
                }
            }
        }
    }
}

// ---------------------------------------------------------------------------
// Kernel 2: flash-style attention, barrier-free.
// Grid: (ceil(SQ/64), B*H). Block: 256 = 4 waves; wave owns 16 q-rows.
// Q,K fragments direct from global; V^T fragments direct from global.
// P round-trips through wave-private rotation-swizzled LDS (conflict-free).
// Softmax: block-shared max (6 swizzles), exp2 domain, row-sums via ones-MFMA.
// ---------------------------------------------------------------------------
__global__ __launch_bounds__(256) void attn_kernel(
    const f16* __restrict__ Q,   // [B*H, SQ, DH]
    const f16* __restrict__ K,   // [B*H, SQ, DH]
    const f16* __restrict__ Vt,  // [B*H, DH, SP]
    float* __restrict__ out)     // [B, SQ, DM]
{
    // Rotation swizzle: P[m][c] stored at [m][ ((c>>4)+(m>>2))&3)*16 + (c&15) ].
    // Writes: 2-way (free). b128 reads: exact 8-phase minimum, conflict-free.
    __shared__ f16 Pl[4][16][64];

    const int q0   = blockIdx.x * 64;
    const int bh   = blockIdx.y;
    const int b    = bh >> 4;
    const int h    = bh & 15;
    const int t    = threadIdx.x;
    const int lane = t & 63;
    const int wid  = t >> 6;
    const int lr   = lane & 15;
    const int quad = lane >> 4;

    const f16* Qb = Q  + (size_t)bh * SQ * DH;
    const f16* Kb = K  + (size_t)bh * SQ * DH;
    const f16* Vb = Vt + (size_t)bh * DH * SP;

    // Q A-fragments, pre-scaled by 0.125*log2(e) (softmax in exp2 domain)
    int qrow = q0 + wid * 16 + lr;
    const int qrow_c = (qrow < SQ) ? qrow : (SQ - 1);
    const f16 qs = (f16)0.1803368801f;   // 1/8 * log2(e)
    f16x8 qf0 = *(const f16x8*)(Qb + (size_t)qrow_c * DH + quad * 8);
    f16x8 qf1 = *(const f16x8*)(Qb + (size_t)qrow_c * DH + 32 + quad * 8);
    qf0 = qf0 * qs;
    qf1 = qf1 * qs;

    const f16x8 ones = (f16x8){(f16)1.f, (f16)1.f, (f16)1.f, (f16)1.f,
                               (f16)1.f, (f16)1.f, (f16)1.f, (f16)1.f};

    f32x4 o[4];
#pragma unroll
    for (int i = 0; i < 4; i++) o[i] = (f32x4){0.f, 0.f, 0.f, 0.f};
    f32x4 lsum = (f32x4){0.f, 0.f, 0.f, 0.f};
    float mrun = -__builtin_inff();

    for (int j0 = 0; j0 < SQ; j0 += 64) {
        // --- scores: S^ = (Q*scale) K^T in exp2 domain; C-layout ---
        f32x4 s4[4];
#pragma unroll
        for (int nb = 0; nb < 4; nb++) {
            const int krow = j0 + nb * 16 + lr;
            const int krow_c = (krow < SQ) ? krow : (SQ - 1);
            const f16x8 kf0 = *(const f16x8*)(Kb + (size_t)krow_c * DH + quad * 8);
            const f16x8 kf1 = *(const f16x8*)(Kb + (size_t)krow_c * DH + 32 + quad * 8);
            f32x4 s = (f32x4){0.f, 0.f, 0.f, 0.f};
            s = MFMA_16x16x32_F16(qf0, kf0, s);
            s = MFMA_16x16x32_F16(qf1, kf1, s);
            s4[nb] = s;
        }
        if (j0 + 64 > SQ) {           // tail tile: mask invalid keys
#pragma unroll
            for (int nb = 0; nb < 4; nb++)
                if (j0 + nb * 16 + lr >= SQ)
#pragma unroll
                    for (int r = 0; r < 4; r++)
                        s4[nb][r] = -__builtin_inff();
        }

        // --- block-shared max over the wave's 16x64 tile ---
        float M = s4[0][0];
#pragma unroll
        for (int nb = 0; nb < 4; nb++)
#pragma unroll
            for (int r = 0; r < 4; r++) M = fmaxf(M, s4[nb][r]);
#pragma unroll
        for (int off = 1; off < 64; off <<= 1)
            M = fmaxf(M, __shfl_xor(M, off, 64));
        const float mnew  = fmaxf(mrun, M);
        const float alpha = __builtin_amdgcn_exp2f(mrun - mnew);  // iter0: 0
        mrun = mnew;

        // --- P = exp2(s - mnew) -> swizzled LDS (wave-private, no barrier) ---
#pragma unroll
        for (int nb = 0; nb < 4; nb++) {
            const int pb = ((nb + quad) & 3) << 4;
#pragma unroll
            for (int r = 0; r < 4; r++)
                Pl[wid][quad * 4 + r][pb + lr] =
                    (f16)__builtin_amdgcn_exp2f(s4[nb][r] - mnew);
        }

        // --- rescale running state ---
#pragma unroll
        for (int d = 0; d < 4; d++)
#pragma unroll
            for (int r = 0; r < 4; r++) o[d][r] *= alpha;
#pragma unroll
        for (int r = 0; r < 4; r++) lsum[r] *= alpha;

        // --- read P as A-fragments (swizzled addresses) ---
        const int rb  = (lr >> 2);
        const int pb0 = ((((quad >> 1) + rb) & 3) << 4) + ((quad & 1) << 3);
        const int pb1 = (((2 + (quad >> 1) + rb) & 3) << 4) + ((quad & 1) << 3);
        const f16x8 pf0 = *(const f16x8*)&Pl[wid][lr][pb0];
        const f16x8 pf1 = *(const f16x8*)&Pl[wid][lr][pb1];

        // row sums via ones-MFMA (C-layout matches o)
        lsum = MFMA_16x16x32_F16(pf0, ones, lsum);
        lsum = MFMA_16x16x32_F16(pf1, ones, lsum);

        // --- PV: V^T B-fragments direct from global ---
        const int cb0 = j0 + quad * 8;                        // <= 1368 always
        int cb1 = j0 + 32 + quad * 8;
        if (cb1 > SP - 8) cb1 = SP - 8;                       // tail clamp (P=0 there)
#pragma unroll
        for (int db = 0; db < 4; db++) {
            const f16* vrow = Vb + (size_t)(db * 16 + lr) * SP;
            const f16x8 vf0 = *(const f16x8*)(vrow + cb0);
            const f16x8 vf1 = *(const f16x8*)(vrow + cb1);
            o[db] = MFMA_16x16x32_F16(pf0, vf0, o[db]);
            o[db] = MFMA_16x16x32_F16(pf1, vf1, o[db]);
        }
    }

    // --- epilogue: normalize, write fp32 [B, S, H*DH] ---
#pragma unroll
    for (int r = 0; r < 4; r++) {
        const int srow_q = q0 + wid * 16 + quad * 4 + r;
        if (srow_q < SQ) {
            const float inv = 1.0f / lsum[r];
#pragma unroll
            for (int db = 0; db < 4; db++)
                out[((size_t)(b * SQ + srow_q)) * DM + h * DH + db * 16 + lr] =
                    o[db][r] * inv;
        }
    }
}

// ---------------------------------------------------------------------------
extern "C" void kernel_launch(void* const* d_in, const int* in_sizes, int n_in,
                              void* d_out, int out_size, void* d_ws, size_t ws_size,
                              hipStream_t stream) {
    const float* hs = (const float*)d_in[0];
    const float* Wq = (const float*)d_in[1];
    const float* bq = (const float*)d_in[2];
    const float* Wk = (const float*)d_in[3];
    const float* bk = (const float*)d_in[4];
    const float* Wv = (const float*)d_in[5];
    const float* bv = (const float*)d_in[6];
    float* out = (float*)d_out;

    // Workspace: Q,K f16 [B*H,SQ,DH] + V^T f16 [B*H,DH,SP]  (~67.4 MB)
    const size_t qk_elems = (size_t)NBATCH * NHEADS * SQ * DH;
    f16* Qw  = (f16*)d_ws;
    f16* Kw  = Qw + qk_elems;
    f16* Vtw = Kw + qk_elems;

    dim3 ggemm((MROWS + 127) / 128, DM / 128, 3);   // (86, 8, 3)
    qkv_gemm_kernel<<<ggemm, 256, 0, stream>>>(hs, Wq, bq, Wk, bk, Wv, bv,
                                               Qw, Kw, Vtw);

    dim3 gattn((SQ + 63) / 64, NBATCH * NHEADS);    // (22, 128)
    attn_kernel<<<gattn, 256, 0, stream>>>(Qw, Kw, Vtw, out);
}

// Round 4
// 394.021 us; speedup vs baseline: 1.6034x; 1.6034x over previous
//
#include <hip/hip_runtime.h>
#include <stdint.h>
#include <stddef.h>

// Problem constants (DINOv2 self-attention)
#define SQ     1370              // sequence length
#define SP     1408              // padded V^T row stride (covers 22 j-tiles of 64)
#define NJ     22                // ceil(SQ/64) key tiles
#define NBATCH 8
#define NHEADS 16
#define DH     64                // head dim
#define DM     1024              // model dim
#define MROWS  (NBATCH * SQ)     // 10960 flattened rows

typedef _Float16 f16;
typedef __attribute__((ext_vector_type(8))) _Float16 f16x8;
typedef __attribute__((ext_vector_type(4))) _Float16 f16x4;
typedef __attribute__((ext_vector_type(4))) float    f32x4;

#define MFMA_16x16x32_F16(a, b, c) __builtin_amdgcn_mfma_f32_16x16x32_f16((a), (b), (c), 0, 0, 0)

// Async global->LDS DMA, 16 B per lane. LDS side must be wave-uniform base +
// lane*16 (hardware constraint); the global side is an ordinary per-lane addr.
__device__ __forceinline__ void load_lds_16(const f16* g, f16* l) {
    __builtin_amdgcn_global_load_lds(
        (const __attribute__((address_space(1))) void*)g,
        (__attribute__((address_space(3))) void*)l, 16, 0, 0);
}

// ---------------------------------------------------------------------------
// Kernel 0: fp32 -> f16 convert (hs + the three weight matrices).
// blockIdx.y selects the segment; grid-stride float4 -> f16x4.
// ---------------------------------------------------------------------------
__global__ __launch_bounds__(256) void cvt_kernel(
    const float* __restrict__ s0, const float* __restrict__ s1,
    const float* __restrict__ s2, const float* __restrict__ s3,
    f16* __restrict__ d0, f16* __restrict__ d1,
    f16* __restrict__ d2, f16* __restrict__ d3,
    int n0, int n1, int n2, int n3)     // counts in float4 units
{
    const float* s; f16* d; int n;
    switch (blockIdx.y) {
        case 0:  s = s0; d = d0; n = n0; break;
        case 1:  s = s1; d = d1; n = n1; break;
        case 2:  s = s2; d = d2; n = n2; break;
        default: s = s3; d = d3; n = n3; break;
    }
    const int stride = gridDim.x * blockDim.x;
    for (int i = blockIdx.x * blockDim.x + threadIdx.x; i < n; i += stride) {
        const float4 v = ((const float4*)s)[i];
        ((f16x4*)d)[i] = (f16x4){(f16)v.x, (f16)v.y, (f16)v.z, (f16)v.w};
    }
}

// ---------------------------------------------------------------------------
// Kernel 1: QKV projection GEMM, pure f16 inputs (m97-style).
//   out[m,n] = sum_k A[m,k] * W[n,k] + bias[n]
// Staging via global_load_lds width 16, BK=32, tile 128x128, 4 waves.
// LDS tiles [128][32] f16 unpadded; chunk-XOR swizzle (phys = logical ^
// ((row>>1)&3)) applied on the GLOBAL source so fragment reads are 2-way
// bank-aliased (free) while the LDS DMA dest stays lane-linear.
// Q,K written [B*H, S, DH]; V written transposed [B*H, DH, SP].
// ---------------------------------------------------------------------------
__global__ __launch_bounds__(256) void qkv_gemm_kernel(
    const f16* __restrict__ A,        // [MROWS][DM] f16
    const f16* __restrict__ Wq16, const f16* __restrict__ Wk16,
    const f16* __restrict__ Wv16,
    const float* __restrict__ bq, const float* __restrict__ bk,
    const float* __restrict__ bv,
    f16* __restrict__ Qo, f16* __restrict__ Ko, f16* __restrict__ Vto)
{
    __shared__ f16 As[128 * 32];
    __shared__ f16 Bs[128 * 32];

    const f16* W; const float* bias;
    if (blockIdx.z == 0)      { W = Wq16; bias = bq; }
    else if (blockIdx.z == 1) { W = Wk16; bias = bk; }
    else                      { W = Wv16; bias = bv; }

    const int m0   = blockIdx.x * 128;
    const int n0   = blockIdx.y * 128;
    const int t    = threadIdx.x;
    const int lane = t & 63;
    const int wid  = t >> 6;
    const int wm   = (wid >> 1) * 64;
    const int wn   = (wid & 1) * 64;
    const int lr   = lane & 15;
    const int quad = lane >> 4;

    f32x4 acc[4][4];
#pragma unroll
    for (int i = 0; i < 4; i++)
#pragma unroll
        for (int j = 0; j < 4; j++) acc[i][j] = (f32x4){0.f, 0.f, 0.f, 0.f};

    // Staging: chunk c (of 512 16B chunks per tile) -> row c>>2, phys chunk
    // c&3, logical chunk (c&3)^((c>>3)&3). Thread t handles c = t and t+256.
    const int c0 = t, c1 = t + 256;
    const int r0 = c0 >> 2, r1 = c1 >> 2;
    const int lc0 = ((c0 & 3) ^ ((c0 >> 3) & 3)) * 8;
    const int lc1 = ((c1 & 3) ^ ((c1 >> 3) & 3)) * 8;
    int am0 = m0 + r0; if (am0 >= MROWS) am0 = MROWS - 1;   // clamp tail rows
    int am1 = m0 + r1; if (am1 >= MROWS) am1 = MROWS - 1;
    const f16* asrc0 = A + (size_t)am0 * DM + lc0;
    const f16* asrc1 = A + (size_t)am1 * DM + lc1;
    const f16* bsrc0 = W + (size_t)(n0 + r0) * DM + lc0;
    const f16* bsrc1 = W + (size_t)(n0 + r1) * DM + lc1;

    // Fragment-read swizzle (uniform per lane): phys chunk = quad ^ ((lr>>1)&3)
    const int fph = (quad ^ ((lr >> 1) & 3)) * 8;

    for (int k0 = 0; k0 < DM; k0 += 32) {
        __syncthreads();                         // prev compute reads done
        load_lds_16(asrc0 + k0, As + c0 * 8);
        load_lds_16(asrc1 + k0, As + c1 * 8);
        load_lds_16(bsrc0 + k0, Bs + c0 * 8);
        load_lds_16(bsrc1 + k0, Bs + c1 * 8);
        __syncthreads();                         // vmcnt drained before barrier

        f16x8 af[4], bf[4];
#pragma unroll
        for (int i = 0; i < 4; i++) {
            af[i] = *(const f16x8*)&As[(wm + i * 16 + lr) * 32 + fph];
            bf[i] = *(const f16x8*)&Bs[(wn + i * 16 + lr) * 32 + fph];
        }
#pragma unroll
        for (int i = 0; i < 4; i++)
#pragma unroll
            for (int j = 0; j < 4; j++)
                acc[i][j] = MFMA_16x16x32_F16(af[i], bf[j], acc[i][j]);
    }

    // Epilogue. C/D layout: row = quad*4+reg, col = lane&15 (m89-verified).
#pragma unroll
    for (int j = 0; j < 4; j++) {
        const int n  = n0 + wn + j * 16 + lr;
        const float bv_ = bias[n];
        const int h = n >> 6, d = n & 63;
#pragma unroll
        for (int i = 0; i < 4; i++) {
#pragma unroll
            for (int r = 0; r < 4; r++) {
                const int m = m0 + wm + i * 16 + quad * 4 + r;
                if (m < MROWS) {
                    const int b = m / SQ, s = m % SQ;
                    const f16 val = (f16)(acc[i][j][r] + bv_);
                    if (blockIdx.z == 2) {
                        Vto[((size_t)((b * NHEADS + h) * DH + d)) * SP + s] = val;
                    } else {
                        f16* outp = (blockIdx.z == 0) ? Qo : Ko;
                        outp[(((size_t)(b * NHEADS + h)) * SQ + s) * DH + d] = val;
                    }
                }
            }
        }
    }
}

// ---------------------------------------------------------------------------
// Kernel 2: flash attention, LDS-staged K/V with double buffering.
// Grid: (ceil(SQ/128)=11, 128 bh). Block 256 = 4 waves; wave owns 32 q-rows
// (two 16-row blocks). K tile [64 keys][64 d] and V^T tile [64 d][64 keys]
// staged via global_load_lds (chunk XOR row&7 source swizzle -> conflict-free
// unpadded fragment reads), double-buffered so tile j+1 DMA overlaps tile j.
// P round-trips through wave-private rotation-swizzled LDS. Softmax: wave-
// shared max, exp2 domain, row sums via ones-MFMA.
// ---------------------------------------------------------------------------
__global__ __launch_bounds__(256) void attn_kernel(
    const f16* __restrict__ Q,   // [B*H, SQ, DH]
    const f16* __restrict__ K,   // [B*H, SQ, DH]
    const f16* __restrict__ Vt,  // [B*H, DH, SP]
    float* __restrict__ out)     // [B, SQ, DM]
{
    __shared__ f16 Kt[2][64 * 64];    // [buf][key][d-chunks swizzled]
    __shared__ f16 Vs[2][64 * 64];    // [buf][d][key-chunks swizzled]
    __shared__ f16 Pl[4][32][64];     // per-wave P, rotation swizzle

    const int q0   = blockIdx.x * 128;
    const int bh   = blockIdx.y;
    const int b    = bh >> 4;
    const int h    = bh & 15;
    const int t    = threadIdx.x;
    const int lane = t & 63;
    const int wid  = t >> 6;
    const int lr   = lane & 15;
    const int quad = lane >> 4;

    const f16* Qb = Q  + (size_t)bh * SQ * DH;
    const f16* Kb = K  + (size_t)bh * SQ * DH;
    const f16* Vb = Vt + (size_t)bh * DH * SP;

    // Q A-fragments for 2 row-blocks, pre-scaled by 0.125*log2(e)
    const f16 qs = (f16)0.1803368801f;
    f16x8 qf[2][2];
#pragma unroll
    for (int rb = 0; rb < 2; rb++) {
        int qrow = q0 + wid * 32 + rb * 16 + lr;
        if (qrow >= SQ) qrow = SQ - 1;
        qf[rb][0] = *(const f16x8*)(Qb + (size_t)qrow * DH + quad * 8) * qs;
        qf[rb][1] = *(const f16x8*)(Qb + (size_t)qrow * DH + 32 + quad * 8) * qs;
    }

    const f16x8 ones = (f16x8){(f16)1.f, (f16)1.f, (f16)1.f, (f16)1.f,
                               (f16)1.f, (f16)1.f, (f16)1.f, (f16)1.f};

    f32x4 o[2][4];
#pragma unroll
    for (int rb = 0; rb < 2; rb++)
#pragma unroll
        for (int d = 0; d < 4; d++) o[rb][d] = (f32x4){0.f, 0.f, 0.f, 0.f};
    f32x4 lsum[2] = {(f32x4){0.f, 0.f, 0.f, 0.f}, (f32x4){0.f, 0.f, 0.f, 0.f}};
    float mrun = -__builtin_inff();

    // Staging: thread t handles phys chunk t&7 of row t>>3 (rows 0..31),
    // second issue covers rows 32..63. Logical chunk = phys ^ (row&7).
    const int srow = t >> 3;
    const int slc  = ((t & 7) ^ (srow & 7)) * 8;
    const f16* ksrc = Kb + (size_t)srow * DH + slc;          // + j0*DH per tile
    const f16* vsrc = Vb + (size_t)srow * SP + slc;          // + j0 per tile

    // Fragment-read phys chunks (uniform per lane): logical quad / 4+quad
    const int fp0 = ((quad)     ^ (lr & 7)) * 8;
    const int fp1 = ((quad + 4) ^ (lr & 7)) * 8;

#define STAGE(bufi, j0)                                                        \
    do {                                                                       \
        load_lds_16(ksrc + (size_t)(j0) * DH, &Kt[bufi][0] + t * 8);           \
        load_lds_16(ksrc + (size_t)((j0) + 32) * DH, &Kt[bufi][2048] + t * 8); \
        load_lds_16(vsrc + (j0), &Vs[bufi][0] + t * 8);                        \
        load_lds_16(vsrc + 32 * SP + (j0), &Vs[bufi][2048] + t * 8);           \
    } while (0)

    STAGE(0, 0);
    int buf = 0;

    for (int jt = 0; jt < NJ; ++jt) {
        const int j0 = jt * 64;
        __syncthreads();                       // buf staged (vmcnt drains here)
        if (jt + 1 < NJ) STAGE(buf ^ 1, j0 + 64);

        // K B-fragments (shared by both row-blocks)
        f16x8 kf[4][2];
#pragma unroll
        for (int nb = 0; nb < 4; nb++) {
            kf[nb][0] = *(const f16x8*)&Kt[buf][(nb * 16 + lr) * 64 + fp0];
            kf[nb][1] = *(const f16x8*)&Kt[buf][(nb * 16 + lr) * 64 + fp1];
        }

        // Scores (exp2 domain), C-layout
        f32x4 s[2][4];
#pragma unroll
        for (int rb = 0; rb < 2; rb++)
#pragma unroll
            for (int nb = 0; nb < 4; nb++) {
                f32x4 acc = (f32x4){0.f, 0.f, 0.f, 0.f};
                acc = MFMA_16x16x32_F16(qf[rb][0], kf[nb][0], acc);
                acc = MFMA_16x16x32_F16(qf[rb][1], kf[nb][1], acc);
                s[rb][nb] = acc;
            }
        if (jt == NJ - 1) {                    // mask tail keys
#pragma unroll
            for (int nb = 0; nb < 4; nb++)
                if (j0 + nb * 16 + lr >= SQ)
#pragma unroll
                    for (int rb = 0; rb < 2; rb++)
#pragma unroll
                        for (int r = 0; r < 4; r++)
                            s[rb][nb][r] = -__builtin_inff();
        }

        // Wave-shared max over the 32x64 tile
        float M = s[0][0][0];
#pragma unroll
        for (int rb = 0; rb < 2; rb++)
#pragma unroll
            for (int nb = 0; nb < 4; nb++)
#pragma unroll
                for (int r = 0; r < 4; r++) M = fmaxf(M, s[rb][nb][r]);
#pragma unroll
        for (int off = 1; off < 64; off <<= 1)
            M = fmaxf(M, __shfl_xor(M, off, 64));
        const float mnew  = fmaxf(mrun, M);
        const float alpha = __builtin_amdgcn_exp2f(mrun - mnew);  // iter0: 0
        mrun = mnew;

        // P = exp2(s - mnew) -> swizzled wave-private LDS (no barrier)
#pragma unroll
        for (int rb = 0; rb < 2; rb++)
#pragma unroll
            for (int nb = 0; nb < 4; nb++) {
                const int pb = ((nb + quad) & 3) << 4;
#pragma unroll
                for (int r = 0; r < 4; r++)
                    Pl[wid][rb * 16 + quad * 4 + r][pb + lr] =
                        (f16)__builtin_amdgcn_exp2f(s[rb][nb][r] - mnew);
            }

        // Rescale running state
#pragma unroll
        for (int rb = 0; rb < 2; rb++) {
#pragma unroll
            for (int d = 0; d < 4; d++)
#pragma unroll
                for (int r = 0; r < 4; r++) o[rb][d][r] *= alpha;
#pragma unroll
            for (int r = 0; r < 4; r++) lsum[rb][r] *= alpha;
        }

        // V^T B-fragments (shared by both row-blocks)
        f16x8 vf[4][2];
#pragma unroll
        for (int db = 0; db < 4; db++) {
            vf[db][0] = *(const f16x8*)&Vs[buf][(db * 16 + lr) * 64 + fp0];
            vf[db][1] = *(const f16x8*)&Vs[buf][(db * 16 + lr) * 64 + fp1];
        }

        // P A-fragments (rotation-swizzled addresses) + lsum + PV
        const int rbk = lr >> 2;
        const int pb0 = ((((quad >> 1) + rbk) & 3) << 4) + ((quad & 1) << 3);
        const int pb1 = (((2 + (quad >> 1) + rbk) & 3) << 4) + ((quad & 1) << 3);
#pragma unroll
        for (int rb = 0; rb < 2; rb++) {
            const f16x8 pf0 = *(const f16x8*)&Pl[wid][rb * 16 + lr][pb0];
            const f16x8 pf1 = *(const f16x8*)&Pl[wid][rb * 16 + lr][pb1];
            lsum[rb] = MFMA_16x16x32_F16(pf0, ones, lsum[rb]);
            lsum[rb] = MFMA_16x16x32_F16(pf1, ones, lsum[rb]);
#pragma unroll
            for (int db = 0; db < 4; db++) {
                o[rb][db] = MFMA_16x16x32_F16(pf0, vf[db][0], o[rb][db]);
                o[rb][db] = MFMA_16x16x32_F16(pf1, vf[db][1], o[rb][db]);
            }
        }
        buf ^= 1;
    }
#undef STAGE

    // Epilogue: normalize, write fp32 [B, S, H*DH]
#pragma unroll
    for (int rb = 0; rb < 2; rb++)
#pragma unroll
        for (int r = 0; r < 4; r++) {
            const int srow_q = q0 + wid * 32 + rb * 16 + quad * 4 + r;
            if (srow_q < SQ) {
                const float inv = 1.0f / lsum[rb][r];
#pragma unroll
                for (int db = 0; db < 4; db++)
                    out[((size_t)(b * SQ + srow_q)) * DM + h * DH + db * 16 + lr] =
                        o[rb][db][r] * inv;
            }
        }
}

// ---------------------------------------------------------------------------
extern "C" void kernel_launch(void* const* d_in, const int* in_sizes, int n_in,
                              void* d_out, int out_size, void* d_ws, size_t ws_size,
                              hipStream_t stream) {
    const float* hs = (const float*)d_in[0];
    const float* Wq = (const float*)d_in[1];
    const float* bq = (const float*)d_in[2];
    const float* Wk = (const float*)d_in[3];
    const float* bk = (const float*)d_in[4];
    const float* Wv = (const float*)d_in[5];
    const float* bv = (const float*)d_in[6];
    float* out = (float*)d_out;

    // Workspace layout (f16), total ~96.7 MB:
    //   Qw, Kw       [B*H, SQ, DH]      2 x 11,223,040
    //   Vtw          [B*H, DH, SP]      11,534,336
    //   hs16         [MROWS, DM]        11,223,040
    //   Wq16/Wk16/Wv16 [DM, DM]         3 x 1,048,576
    const size_t qk_elems = (size_t)NBATCH * NHEADS * SQ * DH;
    const size_t vt_elems = (size_t)NBATCH * NHEADS * DH * SP;
    const size_t hs_elems = (size_t)MROWS * DM;
    const size_t w_elems  = (size_t)DM * DM;
    f16* Qw   = (f16*)d_ws;
    f16* Kw   = Qw + qk_elems;
    f16* Vtw  = Kw + qk_elems;
    f16* hs16 = Vtw + vt_elems;
    f16* Wq16 = hs16 + hs_elems;
    f16* Wk16 = Wq16 + w_elems;
    f16* Wv16 = Wk16 + w_elems;

    dim3 gcvt(512, 4);
    cvt_kernel<<<gcvt, 256, 0, stream>>>(hs, Wq, Wk, Wv,
                                         hs16, Wq16, Wk16, Wv16,
                                         (int)(hs_elems / 4), (int)(w_elems / 4),
                                         (int)(w_elems / 4), (int)(w_elems / 4));

    dim3 ggemm((MROWS + 127) / 128, DM / 128, 3);   // (86, 8, 3)
    qkv_gemm_kernel<<<ggemm, 256, 0, stream>>>(hs16, Wq16, Wk16, Wv16,
                                               bq, bk, bv, Qw, Kw, Vtw);

    dim3 gattn((SQ + 127) / 128, NBATCH * NHEADS);  // (11, 128)
    attn_kernel<<<gattn, 256, 0, stream>>>(Qw, Kw, Vtw, out);
}